// Round 14
// baseline (419.067 us; speedup 1.0000x reference)
//
#include <hip/hip_runtime.h>

typedef _Float16 f16;
typedef __attribute__((ext_vector_type(8))) _Float16 h8v;   // 8 fp16 = 4 VGPR
typedef __attribute__((ext_vector_type(4))) float f4v;      // 16x16 accumulator
typedef __attribute__((ext_vector_type(16))) float f16acc;  // 32x32 accumulator

// fp16 weight workspace layout (elements) — frag-major.
// Q/K/V matrices are PRE-SCALED by -log2(e) so sigmoid = rcp(1+exp2(u)).
#define OFF_WQ  0
#define OFF_WK  2048
#define OFF_WV  4096
#define OFF_AQ1 6144
#define OFF_AK1 22528
#define OFF_AV1 38912
#define OFF_AQ5 55296
#define OFF_AK5 71680
#define OFF_AV5 88064
#define OFF_AO  104448
#define OFF_AO1 120832
#define OFF_AO5 137216      // Ao5 row-major 16x128 (unscaled)
#define WTS_TOTAL 139264

// Padded LDS pitches (f16 elems): rows rotate banks, offsets stay literal.
#define P2 136   // 272 B rows for [64][128] buffers (Xt/Qt/Kt)
#define P1 72    // 144 B rows for V [128][64] and P [64][64]

__device__ __forceinline__ f4v mfma16_(h8v a, h8v b, f4v c) {
  return __builtin_amdgcn_mfma_f32_16x16x32_f16(a, b, c, 0, 0, 0);
}
__device__ __forceinline__ f16acc mfma32_(h8v a, h8v b, f16acc c) {
  return __builtin_amdgcn_mfma_f32_32x32x16_f16(a, b, c, 0, 0, 0);
}
__device__ __forceinline__ float rcp_(float x) { return __builtin_amdgcn_rcpf(x); }
__device__ __forceinline__ float ex2_(float x) {
#if __has_builtin(__builtin_amdgcn_exp2f)
  return __builtin_amdgcn_exp2f(x);      // raw v_exp_f32 (2^x)
#else
  return __expf(x * 0.6931471805599453f);
#endif
}
__device__ __forceinline__ unsigned int pk2(float a, float b) {
  __fp16 __attribute__((ext_vector_type(2))) h2 = __builtin_amdgcn_cvt_pkrtz(a, b);
  return *reinterpret_cast<unsigned int*>(&h2);
}
__device__ __forceinline__ f16acc zero16() {
  f16acc z;
  #pragma unroll
  for (int i = 0; i < 16; ++i) z[i] = 0.f;
  return z;
}

// ACT 0: sigmoid on PRE-SCALED input u (= -log2e * t): rcp(1+2^u)
// ACT 1: silu on natural t. ACT 2: none.
template<int ACT>
__device__ __forceinline__ unsigned long long pack4act(float a, float b, float c, float d) {
  float v[4] = {a, b, c, d};
  #pragma unroll
  for (int j = 0; j < 4; ++j) {
    float t = v[j];
    if (ACT == 0)      t = rcp_(1.0f + ex2_(t));
    else if (ACT == 1) t = t * rcp_(1.0f + ex2_(t * -1.44269504f));
    v[j] = t;
  }
  union { unsigned long long u64; unsigned int u32[2]; } u;
  u.u32[0] = pk2(v[0], v[1]);
  u.u32[1] = pk2(v[2], v[3]);
  return u.u64;
}

// Fused Q,K,V via 32x32x16. Wave w: (rt=w>>1, ct=w&1). X-frags shared by Q/K/V.
// Q^T,K^T -> [n][r] P2; V -> [r][m] P1. All sigmoid (prescaled-domain).
template<int NKK>   // K = NKK*16
__device__ __forceinline__ void qkv_ph(const f16* __restrict__ Wq,
                                       const f16* __restrict__ Wk,
                                       const f16* __restrict__ Wv,
                                       const f16* __restrict__ Xt,
                                       f16* __restrict__ Qt, f16* __restrict__ Kt,
                                       f16* __restrict__ Vb, int w, int lane)
{
  const int l31 = lane & 31, lh = lane >> 5;
  const int rt = w >> 1, ct = w & 1;
  const int xbase = (ct * 32 + l31) * P2 + lh * 8;
  f16acc aq = zero16(), ak = zero16(), av = zero16();
  #pragma unroll
  for (int kk = 0; kk < NKK; ++kk) {
    h8v xf = *(const h8v*)(Xt + xbase + kk * 16);
    const int fo = (rt * NKK + kk) * 512 + lane * 8;
    h8v fq = *(const h8v*)(Wq + fo);
    h8v fk = *(const h8v*)(Wk + fo);
    h8v fv = *(const h8v*)(Wv + fo);
    aq = mfma32_(fq, xf, aq);
    ak = mfma32_(fk, xf, ak);
    av = mfma32_(xf, fv, av);     // V^T = X^T · Wv^T
  }
  const int nrow = (ct * 32 + l31) * P2;
  const int vrow = (rt * 32 + l31) * P1 + ct * 32 + lh * 4;
  #pragma unroll
  for (int q = 0; q < 4; ++q) {
    const int rr = rt * 32 + q * 8 + lh * 4;
    *(unsigned long long*)(Qt + nrow + rr) =
        pack4act<0>(aq[4*q], aq[4*q+1], aq[4*q+2], aq[4*q+3]);
    *(unsigned long long*)(Kt + nrow + rr) =
        pack4act<0>(ak[4*q], ak[4*q+1], ak[4*q+2], ak[4*q+3]);
    *(unsigned long long*)(Vb + vrow + q * 8) =
        pack4act<0>(av[4*q], av[4*q+1], av[4*q+2], av[4*q+3]);
  }
}

// Softmax, all 8 waves, NO max pass, NO internal barrier. Wave pair
// (nst = w&3, mh = w>>2): BOTH waves compute the full 64-m S^T for n-strip nst
// (duplicated MFMA — matrix pipe is underutilized), softmax fully in-register
// (base-2 domain, sum + 2 shfl_xor), then each writes only its mh column-half
// of P. Removes the ssum LDS exchange and one barrier per layer.
__device__ __forceinline__ void softmax_ph(const f16* __restrict__ Qt,
                                           const f16* __restrict__ Kt,
                                           f16* Ps, float is2, int w, int lane)
{
  const int lrow = lane & 15, lk = lane >> 4;
  const int nst = w & 3, mh = w >> 2;
  const int n = nst * 16 + lrow;
  h8v bq[4];
  #pragma unroll
  for (int kk = 0; kk < 4; ++kk)
    bq[kk] = *(const h8v*)(Qt + n * P2 + kk * 32 + lk * 8);
  f4v acc[4];
  #pragma unroll
  for (int mt = 0; mt < 4; ++mt) {
    acc[mt] = (f4v){0.f, 0.f, 0.f, 0.f};
    #pragma unroll
    for (int kk = 0; kk < 4; ++kk) {
      h8v a = *(const h8v*)(Kt + (mt * 16 + lrow) * P2 + kk * 32 + lk * 8);
      acc[mt] = mfma16_(a, bq[kk], acc[mt]);
    }
  }
  // exp2 + full-row sum (16 regs + lane-groups {n, n+16, n+32, n+48})
  float sm = 0.f;
  #pragma unroll
  for (int mt = 0; mt < 4; ++mt)
    #pragma unroll
    for (int j = 0; j < 4; ++j) { acc[mt][j] = ex2_(acc[mt][j] * is2); sm += acc[mt][j]; }
  sm += __shfl_xor(sm, 16);
  sm += __shfl_xor(sm, 32);
  const float inv = rcp_(sm);
  // write only this wave's mh half of the m-columns (pair covers all 64)
  #pragma unroll
  for (int t = 0; t < 2; ++t) {
    const int mt = mh * 2 + t;
    union { unsigned long long u64; unsigned int u32[2]; } u;
    u.u32[0] = pk2(acc[mt][0] * inv, acc[mt][1] * inv);
    u.u32[1] = pk2(acc[mt][2] * inv, acc[mt][3] * inv);
    *(unsigned long long*)(Ps + n * P1 + mt * 16 + lk * 4) = u.u64;
  }
}

// O = V @ P^T via 32x32x16, K=64. Output O^T[n][r] (P2), no act.
__device__ __forceinline__ void pv_ph(const f16* __restrict__ Vb,
                                      const f16* __restrict__ Ps,
                                      f16* __restrict__ Ot, int w, int lane)
{
  const int l31 = lane & 31, lh = lane >> 5;
  const int rt = w >> 1, ct = w & 1;
  f16acc acc = zero16();
  #pragma unroll
  for (int kk = 0; kk < 4; ++kk) {
    h8v a = *(const h8v*)(Vb + (rt * 32 + l31) * P1 + kk * 16 + lh * 8);
    h8v b = *(const h8v*)(Ps + (ct * 32 + l31) * P1 + kk * 16 + lh * 8);
    acc = mfma32_(a, b, acc);
  }
  const int nrow = (ct * 32 + l31) * P2;
  #pragma unroll
  for (int q = 0; q < 4; ++q)
    *(unsigned long long*)(Ot + nrow + rt * 32 + q * 8 + lh * 4) =
        pack4act<2>(acc[4*q], acc[4*q+1], acc[4*q+2], acc[4*q+3]);
}

// R = silu(Ao @ O) via 32x32x16, K=128. Output R^T[n][s] (P2) -> Rt.
__device__ __forceinline__ void ao_ph(const f16* __restrict__ Ao,
                                      const f16* __restrict__ Ot,
                                      f16* __restrict__ Rt, int w, int lane)
{
  const int l31 = lane & 31, lh = lane >> 5;
  const int st = w >> 1, ct = w & 1;
  f16acc acc = zero16();
  #pragma unroll
  for (int kk = 0; kk < 8; ++kk) {
    h8v a = *(const h8v*)(Ao + (st * 8 + kk) * 512 + lane * 8);
    h8v b = *(const h8v*)(Ot + (ct * 32 + l31) * P2 + kk * 16 + lh * 8);
    acc = mfma32_(a, b, acc);
  }
  const int nrow = (ct * 32 + l31) * P2;
  #pragma unroll
  for (int q = 0; q < 4; ++q)
    *(unsigned long long*)(Rt + nrow + st * 32 + q * 8 + lh * 4) =
        pack4act<1>(acc[4*q], acc[4*q+1], acc[4*q+2], acc[4*q+3]);
}

// Final (Mw-fused): M[g][i][n] = sum_j silu(Ao5 @ O)[g*4+j][n] — channel-sum
// done in-register. Waves 0..3 (n-strip w); lane: g=lk, n=16w+lrow.
// Mw layout: [s][g][i][n], s = b>>6, i = b&63.
__device__ __forceinline__ void final_ph(const f16* __restrict__ Ao5g,
                                         const f16* __restrict__ Ot,
                                         float* __restrict__ Mw, int b, int w, int lane)
{
  const int lrow = lane & 15, lk = lane >> 4;
  h8v a[4];
  #pragma unroll
  for (int kk = 0; kk < 4; ++kk)
    a[kk] = *(const h8v*)(Ao5g + lrow * 128 + kk * 32 + lk * 8);
  const int n = 16 * w + lrow;
  f4v acc = {0.f, 0.f, 0.f, 0.f};
  #pragma unroll
  for (int kk = 0; kk < 4; ++kk) {
    h8v bb = *(const h8v*)(Ot + n * P2 + kk * 32 + lk * 8);
    acc = mfma16_(a[kk], bb, acc);
  }
  float msum = 0.f;
  #pragma unroll
  for (int j = 0; j < 4; ++j) {
    float v = acc[j];
    v = v * rcp_(1.0f + ex2_(v * -1.44269504f));
    msum += v;                     // sum over s = lk*4+j within channel-group lk
  }
  Mw[(size_t)(b >> 6) * 16384 + lk * 4096 + (b & 63) * 64 + n] = msum;
}

__global__ __launch_bounds__(512, 4)
void swarm_attn_mfma(const float* __restrict__ x, const float* __restrict__ L,
                     const f16* __restrict__ wts, float* __restrict__ Mw)
{
  __shared__ f16 Xt[64 * P2];    // X^T / R^T [n][k]; Ps aliases this buffer
  __shared__ f16 Qt[64 * P2];    // Q^T [n][r]; reused as O^T after softmax
  __shared__ f16 Kt[64 * P2];    // K^T [m][r]
  __shared__ f16 Vb[128 * P1];   // V [r][m]
  f16* Ps = Xt;                  // P [n][m] pitch P1 (Xt dead during softmax/PV)

  const int b = blockIdx.x;
  const int tid = threadIdx.x;
  const int w = tid >> 6, lane = tid & 63;

  // stage layer-1 X^T [n][f], zero-padded to K=16
  {
    const int n = tid >> 3, c = tid & 7;
    unsigned int val = 0;
    if (c < 4) {
      const float a  = x[(size_t)b * 512 + (2 * c) * 64 + n];
      const float bb = x[(size_t)b * 512 + (2 * c + 1) * 64 + n];
      val = pk2(a, bb);
    }
    *(unsigned int*)(Xt + n * P2 + 2 * c) = val;
  }
  // every wave computes is2 itself (L is L2-resident; no LDS broadcast needed)
  const float lv = L[(size_t)b * 512 + lane];
  const unsigned long long msk = __ballot(lv >= 1.0f);
  const float is2 = __frsqrt_rn((float)(__popcll(msk) + 1)) * 1.44269504f;
  __syncthreads();

  // -------- Layer 1 (K = 16 padded) --------
  qkv_ph<1>(wts + OFF_WQ, wts + OFF_WK, wts + OFF_WV, Xt, Qt, Kt, Vb, w, lane);
  __syncthreads();
  softmax_ph(Qt, Kt, Ps, is2, w, lane);
  __syncthreads();
  pv_ph(Vb, Ps, Qt, w, lane);                 // O^T -> Qt
  __syncthreads();
  ao_ph(wts + OFF_AO, Qt, Xt, w, lane);       // R^T -> Xt
  __syncthreads();

  // -------- Layer 2 (K = 128) --------
  qkv_ph<8>(wts + OFF_AQ1, wts + OFF_AK1, wts + OFF_AV1, Xt, Qt, Kt, Vb, w, lane);
  __syncthreads();
  softmax_ph(Qt, Kt, Ps, is2, w, lane);
  __syncthreads();
  pv_ph(Vb, Ps, Qt, w, lane);
  __syncthreads();
  ao_ph(wts + OFF_AO1, Qt, Xt, w, lane);
  __syncthreads();

  // -------- Layer 3 (K = 128) --------
  qkv_ph<8>(wts + OFF_AQ5, wts + OFF_AK5, wts + OFF_AV5, Xt, Qt, Kt, Vb, w, lane);
  __syncthreads();
  softmax_ph(Qt, Kt, Ps, is2, w, lane);
  __syncthreads();
  pv_ph(Vb, Ps, Qt, w, lane);
  __syncthreads();
  if (w < 4) final_ph(wts + OFF_AO5, Qt, Mw, b, w, lane);
}

// Convert weights to fp16, frag-major; Q/K/V matrices pre-scaled by -log2(e).
__global__ void conv_wts(const float* Aq, const float* Ak, const float* Av,
                         const float* Aq1, const float* Ak1, const float* Av1,
                         const float* Aq5, const float* Ak5, const float* Av5,
                         const float* Ao, const float* Ao1, const float* Ao5,
                         f16* wts)
{
  const float SCL = -1.44269504088896f;
  const int t = blockIdx.x * 256 + threadIdx.x;
  if (t >= WTS_TOTAL) return;
  float v;
  if (t < 6144) {                       // L1: 128x16 (padded from 8), 4 frags x 512
    const int m = t >> 11, idx = t & 2047;
    const int fi = idx >> 9, rem = idx & 511, lane = rem >> 3, j = rem & 7;
    const int r = fi * 32 + (lane & 31), k = (lane >> 5) * 8 + j;
    const float* W = (m == 0) ? Aq : (m == 1) ? Ak : Av;
    v = (k < 8) ? W[r * 8 + k] * SCL : 0.f;
  } else if (t < 137216) {              // 8 matrices 128x128, 32 frags each
    const int m = (t - 6144) >> 14, idx = (t - 6144) & 16383;
    const int fi = idx >> 9, rem = idx & 511, lane = rem >> 3, j = rem & 7;
    const int rt = fi >> 3, kk = fi & 7;
    const int r = rt * 32 + (lane & 31), k = kk * 16 + (lane >> 5) * 8 + j;
    const float* W = (m == 0) ? Aq1 : (m == 1) ? Ak1 : (m == 2) ? Av1 :
                     (m == 3) ? Aq5 : (m == 4) ? Ak5 : (m == 5) ? Av5 :
                     (m == 6) ? Ao : Ao1;
    v = W[r * 128 + k];
    if (m < 6) v *= SCL;                // sigmoid inputs only
  } else {
    v = Ao5[t - 137216];
  }
  wts[t] = (f16)v;
}

// Stage A: per swarm, row/col sums of squares of M (M already channel-summed)
#define ASTR 65
__global__ __launch_bounds__(256, 1)
void reduce_kernel(const float* __restrict__ Mw,
                   float* __restrict__ rsw, float* __restrict__ csw)
{
  __shared__ float Msh[4 * 64 * ASTR];
  const int s = blockIdx.x, t = threadIdx.x;
  for (int e = t; e < 16384; e += 256) {
    const int j = e & 63, i = (e >> 6) & 63, g = e >> 12;
    Msh[(g * 64 + i) * ASTR + j] = Mw[(size_t)s * 16384 + e];
  }
  __syncthreads();
  const int g = t >> 6, i = t & 63;
  float r2 = 0.f, c2 = 0.f;
  for (int j = 0; j < 64; ++j) {
    const float a = Msh[(g * 64 + i) * ASTR + j];
    const float bb = Msh[(g * 64 + j) * ASTR + i];
    r2 = fmaf(a, a, r2);
    c2 = fmaf(bb, bb, c2);
  }
  rsw[s * 256 + g * 64 + i] = r2;
  csw[s * 256 + g * 64 + i] = c2;
}

// Stage B: fully-parallel expansion to the 256x256 output per swarm
__global__ __launch_bounds__(256, 1)
void expand_kernel(const float* __restrict__ Mw, const float* __restrict__ rsw,
                   const float* __restrict__ csw, float* __restrict__ out)
{
  const size_t e = ((size_t)blockIdx.x * 256 + threadIdx.x) * 4;
  const int s = (int)(e >> 16);
  const int rem = (int)(e & 65535);
  const int u = rem >> 8, v0 = rem & 255;
  const int ub = u >> 7, ii = (u & 127) >> 1, p = u & 1;
  const float* Ms = Mw + (size_t)s * 16384;
  float4 o;
  float* po = &o.x;
  #pragma unroll
  for (int c = 0; c < 4; ++c) {
    const int v = v0 + c;
    const int vb = v >> 7, jj = (v & 127) >> 1, q = v & 1;
    float val = 0.f;
    if (u == v) {
      val = rsw[s * 256 + (2 * ub) * 64 + ii] + rsw[s * 256 + (2 * ub + 1) * 64 + ii]
          + csw[s * 256 + ub * 64 + ii] + csw[s * 256 + (2 + ub) * 64 + ii];
    } else if (p == q) {
      const int g = 2 * ub + vb, gp = 2 * vb + ub;
      const float a = Ms[g * 4096 + ii * 64 + jj];
      const float bb = Ms[gp * 4096 + jj * 64 + ii];
      val = -(a * a + bb * bb);
    }
    po[c] = val;
  }
  *(float4*)(out + e) = o;
}

extern "C" void kernel_launch(void* const* d_in, const int* in_sizes, int n_in,
                              void* d_out, int out_size, void* d_ws, size_t ws_size,
                              hipStream_t stream)
{
  const float* x   = (const float*)d_in[0];
  const float* L   = (const float*)d_in[1];
  const float* Aq  = (const float*)d_in[2];
  const float* Ak  = (const float*)d_in[3];
  const float* Av  = (const float*)d_in[4];
  const float* Aq1 = (const float*)d_in[5];
  const float* Ak1 = (const float*)d_in[6];
  const float* Av1 = (const float*)d_in[7];
  const float* Aq5 = (const float*)d_in[8];
  const float* Ak5 = (const float*)d_in[9];
  const float* Av5 = (const float*)d_in[10];
  const float* Ao  = (const float*)d_in[11];
  const float* Ao1 = (const float*)d_in[12];
  const float* Ao5 = (const float*)d_in[13];

  // ws: fp16 weights (278528 B) | Mw 128*16384 f32 | rsw | csw
  f16* wts = (f16*)d_ws;
  float* Mw  = (float*)((char*)d_ws + (size_t)WTS_TOTAL * 2);
  float* rsw = Mw + (size_t)128 * 16384;
  float* csw = rsw + 128 * 256;

  conv_wts<<<(WTS_TOTAL + 255) / 256, 256, 0, stream>>>(Aq, Ak, Av, Aq1, Ak1, Av1,
                                                        Aq5, Ak5, Av5, Ao, Ao1, Ao5, wts);
  swarm_attn_mfma<<<8192, 512, 0, stream>>>(x, L, wts, Mw);
  reduce_kernel<<<128, 256, 0, stream>>>(Mw, rsw, csw);
  expand_kernel<<<8192, 256, 0, stream>>>(Mw, rsw, csw, (float*)d_out);
}

// Round 15
// 314.689 us; speedup vs baseline: 1.3317x; 1.3317x over previous
//
#include <hip/hip_runtime.h>

typedef _Float16 f16;
typedef __attribute__((ext_vector_type(8))) _Float16 h8v;   // 8 fp16 = 4 VGPR
typedef __attribute__((ext_vector_type(4))) float f4v;      // 16x16 accumulator
typedef __attribute__((ext_vector_type(16))) float f16acc;  // 32x32 accumulator

// fp16 weight workspace layout (elements) — frag-major.
// Q/K/V matrices are PRE-SCALED by -log2(e) so sigmoid = rcp(1+exp2(u)).
#define OFF_WQ  0
#define OFF_WK  2048
#define OFF_WV  4096
#define OFF_AQ1 6144
#define OFF_AK1 22528
#define OFF_AV1 38912
#define OFF_AQ5 55296
#define OFF_AK5 71680
#define OFF_AV5 88064
#define OFF_AO  104448
#define OFF_AO1 120832
#define OFF_AO5 137216      // Ao5 row-major 16x128 (unscaled)
#define WTS_TOTAL 139264

// Padded LDS pitches (f16 elems): rows rotate banks, offsets stay literal.
#define P2 136   // 272 B rows for [64][128] buffers (Xt/Qt/Kt)
#define P1 72    // 144 B rows for V [128][64] and P [64][64]

__device__ __forceinline__ f4v mfma16_(h8v a, h8v b, f4v c) {
  return __builtin_amdgcn_mfma_f32_16x16x32_f16(a, b, c, 0, 0, 0);
}
__device__ __forceinline__ f16acc mfma32_(h8v a, h8v b, f16acc c) {
  return __builtin_amdgcn_mfma_f32_32x32x16_f16(a, b, c, 0, 0, 0);
}
__device__ __forceinline__ float rcp_(float x) { return __builtin_amdgcn_rcpf(x); }
__device__ __forceinline__ float ex2_(float x) {
#if __has_builtin(__builtin_amdgcn_exp2f)
  return __builtin_amdgcn_exp2f(x);      // raw v_exp_f32 (2^x)
#else
  return __expf(x * 0.6931471805599453f);
#endif
}
__device__ __forceinline__ unsigned int pk2(float a, float b) {
  __fp16 __attribute__((ext_vector_type(2))) h2 = __builtin_amdgcn_cvt_pkrtz(a, b);
  return *reinterpret_cast<unsigned int*>(&h2);
}
__device__ __forceinline__ f16acc zero16() {
  f16acc z;
  #pragma unroll
  for (int i = 0; i < 16; ++i) z[i] = 0.f;
  return z;
}

// ACT 0: sigmoid on PRE-SCALED input u (= -log2e * t): rcp(1+2^u)
// ACT 1: silu on natural t. ACT 2: none.
template<int ACT>
__device__ __forceinline__ unsigned long long pack4act(float a, float b, float c, float d) {
  float v[4] = {a, b, c, d};
  #pragma unroll
  for (int j = 0; j < 4; ++j) {
    float t = v[j];
    if (ACT == 0)      t = rcp_(1.0f + ex2_(t));
    else if (ACT == 1) t = t * rcp_(1.0f + ex2_(t * -1.44269504f));
    v[j] = t;
  }
  union { unsigned long long u64; unsigned int u32[2]; } u;
  u.u32[0] = pk2(v[0], v[1]);
  u.u32[1] = pk2(v[2], v[3]);
  return u.u64;
}

// Fused Q,K,V via 32x32x16. Wave w: (rt=w>>1, ct=w&1). X-frags shared by Q/K/V.
// Q^T,K^T -> [n][r] P2; V -> [r][m] P1. All sigmoid (prescaled-domain).
template<int NKK>   // K = NKK*16
__device__ __forceinline__ void qkv_ph(const f16* __restrict__ Wq,
                                       const f16* __restrict__ Wk,
                                       const f16* __restrict__ Wv,
                                       const f16* __restrict__ Xt,
                                       f16* __restrict__ Qt, f16* __restrict__ Kt,
                                       f16* __restrict__ Vb, int w, int lane)
{
  const int l31 = lane & 31, lh = lane >> 5;
  const int rt = w >> 1, ct = w & 1;
  const int xbase = (ct * 32 + l31) * P2 + lh * 8;
  f16acc aq = zero16(), ak = zero16(), av = zero16();
  __builtin_amdgcn_s_setprio(1);
  #pragma unroll
  for (int kk = 0; kk < NKK; ++kk) {
    h8v xf = *(const h8v*)(Xt + xbase + kk * 16);
    const int fo = (rt * NKK + kk) * 512 + lane * 8;
    h8v fq = *(const h8v*)(Wq + fo);
    h8v fk = *(const h8v*)(Wk + fo);
    h8v fv = *(const h8v*)(Wv + fo);
    aq = mfma32_(fq, xf, aq);
    ak = mfma32_(fk, xf, ak);
    av = mfma32_(xf, fv, av);     // V^T = X^T · Wv^T
  }
  __builtin_amdgcn_s_setprio(0);
  const int nrow = (ct * 32 + l31) * P2;
  const int vrow = (rt * 32 + l31) * P1 + ct * 32 + lh * 4;
  #pragma unroll
  for (int q = 0; q < 4; ++q) {
    const int rr = rt * 32 + q * 8 + lh * 4;
    *(unsigned long long*)(Qt + nrow + rr) =
        pack4act<0>(aq[4*q], aq[4*q+1], aq[4*q+2], aq[4*q+3]);
    *(unsigned long long*)(Kt + nrow + rr) =
        pack4act<0>(ak[4*q], ak[4*q+1], ak[4*q+2], ak[4*q+3]);
    *(unsigned long long*)(Vb + vrow + q * 8) =
        pack4act<0>(av[4*q], av[4*q+1], av[4*q+2], av[4*q+3]);
  }
}

// Softmax, all 8 waves, NO max pass (f32 range analysis: t <= ~48 -> 2^48 ok),
// ONE internal barrier (sum broadcast). Wave (nst=w&3, mh=w>>2).
// Base-2 domain: p = 2^(S*is2) / sum.
__device__ __forceinline__ void softmax_ph(const f16* __restrict__ Qt,
                                           const f16* __restrict__ Kt,
                                           f16* Ps, float* __restrict__ ssum,
                                           float is2, int w, int lane)
{
  const int lrow = lane & 15, lk = lane >> 4;
  const int nst = w & 3, mh = w >> 2;
  const int n = nst * 16 + lrow;
  h8v bq[4];
  #pragma unroll
  for (int kk = 0; kk < 4; ++kk)
    bq[kk] = *(const h8v*)(Qt + n * P2 + kk * 32 + lk * 8);
  f4v acc[2];
  __builtin_amdgcn_s_setprio(1);
  #pragma unroll
  for (int t = 0; t < 2; ++t) {
    const int mt = mh * 2 + t;
    acc[t] = (f4v){0.f, 0.f, 0.f, 0.f};
    #pragma unroll
    for (int kk = 0; kk < 4; ++kk) {
      h8v a = *(const h8v*)(Kt + (mt * 16 + lrow) * P2 + kk * 32 + lk * 8);
      acc[t] = mfma16_(a, bq[kk], acc[t]);
    }
  }
  __builtin_amdgcn_s_setprio(0);
  float sm = 0.f;
  #pragma unroll
  for (int t = 0; t < 2; ++t)
    #pragma unroll
    for (int j = 0; j < 4; ++j) { acc[t][j] = ex2_(acc[t][j] * is2); sm += acc[t][j]; }
  sm += __shfl_xor(sm, 16);
  sm += __shfl_xor(sm, 32);
  if (lk == 0) ssum[mh * 64 + n] = sm;
  __syncthreads();
  const float inv = rcp_(ssum[n] + ssum[64 + n]);
  #pragma unroll
  for (int t = 0; t < 2; ++t) {
    const int mt = mh * 2 + t;
    union { unsigned long long u64; unsigned int u32[2]; } u;
    u.u32[0] = pk2(acc[t][0] * inv, acc[t][1] * inv);
    u.u32[1] = pk2(acc[t][2] * inv, acc[t][3] * inv);
    *(unsigned long long*)(Ps + n * P1 + mt * 16 + lk * 4) = u.u64;
  }
}

// O = V @ P^T via 32x32x16, K=64. Output O^T[n][r] (P2), no act.
__device__ __forceinline__ void pv_ph(const f16* __restrict__ Vb,
                                      const f16* __restrict__ Ps,
                                      f16* __restrict__ Ot, int w, int lane)
{
  const int l31 = lane & 31, lh = lane >> 5;
  const int rt = w >> 1, ct = w & 1;
  f16acc acc = zero16();
  __builtin_amdgcn_s_setprio(1);
  #pragma unroll
  for (int kk = 0; kk < 4; ++kk) {
    h8v a = *(const h8v*)(Vb + (rt * 32 + l31) * P1 + kk * 16 + lh * 8);
    h8v b = *(const h8v*)(Ps + (ct * 32 + l31) * P1 + kk * 16 + lh * 8);
    acc = mfma32_(a, b, acc);
  }
  __builtin_amdgcn_s_setprio(0);
  const int nrow = (ct * 32 + l31) * P2;
  #pragma unroll
  for (int q = 0; q < 4; ++q)
    *(unsigned long long*)(Ot + nrow + rt * 32 + q * 8 + lh * 4) =
        pack4act<2>(acc[4*q], acc[4*q+1], acc[4*q+2], acc[4*q+3]);
}

// R = silu(Ao @ O) via 32x32x16, K=128. Output R^T[n][s] (P2) -> Rt.
__device__ __forceinline__ void ao_ph(const f16* __restrict__ Ao,
                                      const f16* __restrict__ Ot,
                                      f16* __restrict__ Rt, int w, int lane)
{
  const int l31 = lane & 31, lh = lane >> 5;
  const int st = w >> 1, ct = w & 1;
  f16acc acc = zero16();
  __builtin_amdgcn_s_setprio(1);
  #pragma unroll
  for (int kk = 0; kk < 8; ++kk) {
    h8v a = *(const h8v*)(Ao + (st * 8 + kk) * 512 + lane * 8);
    h8v b = *(const h8v*)(Ot + (ct * 32 + l31) * P2 + kk * 16 + lh * 8);
    acc = mfma32_(a, b, acc);
  }
  __builtin_amdgcn_s_setprio(0);
  const int nrow = (ct * 32 + l31) * P2;
  #pragma unroll
  for (int q = 0; q < 4; ++q)
    *(unsigned long long*)(Rt + nrow + st * 32 + q * 8 + lh * 4) =
        pack4act<1>(acc[4*q], acc[4*q+1], acc[4*q+2], acc[4*q+3]);
}

// Final (Mw-fused): M[g][i][n] = sum_j silu(Ao5 @ O)[g*4+j][n] — channel-sum
// done in-register. Waves 0..3 (n-strip w); lane: g=lk, n=16w+lrow.
// Mw layout: [s][g][i][n], s = b>>6, i = b&63.
__device__ __forceinline__ void final_ph(const f16* __restrict__ Ao5g,
                                         const f16* __restrict__ Ot,
                                         float* __restrict__ Mw, int b, int w, int lane)
{
  const int lrow = lane & 15, lk = lane >> 4;
  h8v a[4];
  #pragma unroll
  for (int kk = 0; kk < 4; ++kk)
    a[kk] = *(const h8v*)(Ao5g + lrow * 128 + kk * 32 + lk * 8);
  const int n = 16 * w + lrow;
  f4v acc = {0.f, 0.f, 0.f, 0.f};
  #pragma unroll
  for (int kk = 0; kk < 4; ++kk) {
    h8v bb = *(const h8v*)(Ot + n * P2 + kk * 32 + lk * 8);
    acc = mfma16_(a[kk], bb, acc);
  }
  float msum = 0.f;
  #pragma unroll
  for (int j = 0; j < 4; ++j) {
    float v = acc[j];
    v = v * rcp_(1.0f + ex2_(v * -1.44269504f));
    msum += v;                     // sum over s = lk*4+j within channel-group lk
  }
  Mw[(size_t)(b >> 6) * 16384 + lk * 4096 + (b & 63) * 64 + n] = msum;
}

__global__ __launch_bounds__(512, 4)
void swarm_attn_mfma(const float* __restrict__ x, const float* __restrict__ L,
                     const f16* __restrict__ wts, float* __restrict__ Mw)
{
  __shared__ f16 Xt[64 * P2];    // X^T / R^T [n][k]; Ps aliases this buffer
  __shared__ f16 Qt[64 * P2];    // Q^T [n][r]; reused as O^T after softmax
  __shared__ f16 Kt[64 * P2];    // K^T [m][r]
  __shared__ f16 Vb[128 * P1];   // V [r][m]
  __shared__ float ssum[2 * 64];
  f16* Ps = Xt;                  // P [n][m] pitch P1 (Xt dead during softmax/PV)

  const int b = blockIdx.x;
  const int tid = threadIdx.x;
  const int w = tid >> 6, lane = tid & 63;

  // stage layer-1 X^T [n][f], zero-padded to K=16
  {
    const int n = tid >> 3, c = tid & 7;
    unsigned int val = 0;
    if (c < 4) {
      const float a  = x[(size_t)b * 512 + (2 * c) * 64 + n];
      const float bb = x[(size_t)b * 512 + (2 * c + 1) * 64 + n];
      val = pk2(a, bb);
    }
    *(unsigned int*)(Xt + n * P2 + 2 * c) = val;
  }
  // every wave computes is2 itself (L is L2-resident; no LDS broadcast needed)
  const float lv = L[(size_t)b * 512 + lane];
  const unsigned long long msk = __ballot(lv >= 1.0f);
  const float is2 = __frsqrt_rn((float)(__popcll(msk) + 1)) * 1.44269504f;
  __syncthreads();

  // -------- Layer 1 (K = 16 padded) --------
  qkv_ph<1>(wts + OFF_WQ, wts + OFF_WK, wts + OFF_WV, Xt, Qt, Kt, Vb, w, lane);
  __syncthreads();
  softmax_ph(Qt, Kt, Ps, ssum, is2, w, lane);
  __syncthreads();
  pv_ph(Vb, Ps, Qt, w, lane);                 // O^T -> Qt
  __syncthreads();
  ao_ph(wts + OFF_AO, Qt, Xt, w, lane);       // R^T -> Xt
  __syncthreads();

  // -------- Layer 2 (K = 128) --------
  qkv_ph<8>(wts + OFF_AQ1, wts + OFF_AK1, wts + OFF_AV1, Xt, Qt, Kt, Vb, w, lane);
  __syncthreads();
  softmax_ph(Qt, Kt, Ps, ssum, is2, w, lane);
  __syncthreads();
  pv_ph(Vb, Ps, Qt, w, lane);
  __syncthreads();
  ao_ph(wts + OFF_AO1, Qt, Xt, w, lane);
  __syncthreads();

  // -------- Layer 3 (K = 128) --------
  qkv_ph<8>(wts + OFF_AQ5, wts + OFF_AK5, wts + OFF_AV5, Xt, Qt, Kt, Vb, w, lane);
  __syncthreads();
  softmax_ph(Qt, Kt, Ps, ssum, is2, w, lane);
  __syncthreads();
  pv_ph(Vb, Ps, Qt, w, lane);
  __syncthreads();
  if (w < 4) final_ph(wts + OFF_AO5, Qt, Mw, b, w, lane);
}

// Convert weights to fp16, frag-major; Q/K/V matrices pre-scaled by -log2(e).
__global__ void conv_wts(const float* Aq, const float* Ak, const float* Av,
                         const float* Aq1, const float* Ak1, const float* Av1,
                         const float* Aq5, const float* Ak5, const float* Av5,
                         const float* Ao, const float* Ao1, const float* Ao5,
                         f16* wts)
{
  const float SCL = -1.44269504088896f;
  const int t = blockIdx.x * 256 + threadIdx.x;
  if (t >= WTS_TOTAL) return;
  float v;
  if (t < 6144) {                       // L1: 128x16 (padded from 8), 4 frags x 512
    const int m = t >> 11, idx = t & 2047;
    const int fi = idx >> 9, rem = idx & 511, lane = rem >> 3, j = rem & 7;
    const int r = fi * 32 + (lane & 31), k = (lane >> 5) * 8 + j;
    const float* W = (m == 0) ? Aq : (m == 1) ? Ak : Av;
    v = (k < 8) ? W[r * 8 + k] * SCL : 0.f;
  } else if (t < 137216) {              // 8 matrices 128x128, 32 frags each
    const int m = (t - 6144) >> 14, idx = (t - 6144) & 16383;
    const int fi = idx >> 9, rem = idx & 511, lane = rem >> 3, j = rem & 7;
    const int rt = fi >> 3, kk = fi & 7;
    const int r = rt * 32 + (lane & 31), k = kk * 16 + (lane >> 5) * 8 + j;
    const float* W = (m == 0) ? Aq1 : (m == 1) ? Ak1 : (m == 2) ? Av1 :
                     (m == 3) ? Aq5 : (m == 4) ? Ak5 : (m == 5) ? Av5 :
                     (m == 6) ? Ao : Ao1;
    v = W[r * 128 + k];
    if (m < 6) v *= SCL;                // sigmoid inputs only
  } else {
    v = Ao5[t - 137216];
  }
  wts[t] = (f16)v;
}

// Stage A: per swarm, row/col sums of squares of M (M already channel-summed)
#define ASTR 65
__global__ __launch_bounds__(256, 1)
void reduce_kernel(const float* __restrict__ Mw,
                   float* __restrict__ rsw, float* __restrict__ csw)
{
  __shared__ float Msh[4 * 64 * ASTR];
  const int s = blockIdx.x, t = threadIdx.x;
  for (int e = t; e < 16384; e += 256) {
    const int j = e & 63, i = (e >> 6) & 63, g = e >> 12;
    Msh[(g * 64 + i) * ASTR + j] = Mw[(size_t)s * 16384 + e];
  }
  __syncthreads();
  const int g = t >> 6, i = t & 63;
  float r2 = 0.f, c2 = 0.f;
  for (int j = 0; j < 64; ++j) {
    const float a = Msh[(g * 64 + i) * ASTR + j];
    const float bb = Msh[(g * 64 + j) * ASTR + i];
    r2 = fmaf(a, a, r2);
    c2 = fmaf(bb, bb, c2);
  }
  rsw[s * 256 + g * 64 + i] = r2;
  csw[s * 256 + g * 64 + i] = c2;
}

// Stage B: fully-parallel expansion to the 256x256 output per swarm
__global__ __launch_bounds__(256, 1)
void expand_kernel(const float* __restrict__ Mw, const float* __restrict__ rsw,
                   const float* __restrict__ csw, float* __restrict__ out)
{
  const size_t e = ((size_t)blockIdx.x * 256 + threadIdx.x) * 4;
  const int s = (int)(e >> 16);
  const int rem = (int)(e & 65535);
  const int u = rem >> 8, v0 = rem & 255;
  const int ub = u >> 7, ii = (u & 127) >> 1, p = u & 1;
  const float* Ms = Mw + (size_t)s * 16384;
  float4 o;
  float* po = &o.x;
  #pragma unroll
  for (int c = 0; c < 4; ++c) {
    const int v = v0 + c;
    const int vb = v >> 7, jj = (v & 127) >> 1, q = v & 1;
    float val = 0.f;
    if (u == v) {
      val = rsw[s * 256 + (2 * ub) * 64 + ii] + rsw[s * 256 + (2 * ub + 1) * 64 + ii]
          + csw[s * 256 + ub * 64 + ii] + csw[s * 256 + (2 + ub) * 64 + ii];
    } else if (p == q) {
      const int g = 2 * ub + vb, gp = 2 * vb + ub;
      const float a = Ms[g * 4096 + ii * 64 + jj];
      const float bb = Ms[gp * 4096 + jj * 64 + ii];
      val = -(a * a + bb * bb);
    }
    po[c] = val;
  }
  *(float4*)(out + e) = o;
}

extern "C" void kernel_launch(void* const* d_in, const int* in_sizes, int n_in,
                              void* d_out, int out_size, void* d_ws, size_t ws_size,
                              hipStream_t stream)
{
  const float* x   = (const float*)d_in[0];
  const float* L   = (const float*)d_in[1];
  const float* Aq  = (const float*)d_in[2];
  const float* Ak  = (const float*)d_in[3];
  const float* Av  = (const float*)d_in[4];
  const float* Aq1 = (const float*)d_in[5];
  const float* Ak1 = (const float*)d_in[6];
  const float* Av1 = (const float*)d_in[7];
  const float* Aq5 = (const float*)d_in[8];
  const float* Ak5 = (const float*)d_in[9];
  const float* Av5 = (const float*)d_in[10];
  const float* Ao  = (const float*)d_in[11];
  const float* Ao1 = (const float*)d_in[12];
  const float* Ao5 = (const float*)d_in[13];

  // ws: fp16 weights (278528 B) | Mw 128*16384 f32 | rsw | csw
  f16* wts = (f16*)d_ws;
  float* Mw  = (float*)((char*)d_ws + (size_t)WTS_TOTAL * 2);
  float* rsw = Mw + (size_t)128 * 16384;
  float* csw = rsw + 128 * 256;

  conv_wts<<<(WTS_TOTAL + 255) / 256, 256, 0, stream>>>(Aq, Ak, Av, Aq1, Ak1, Av1,
                                                        Aq5, Ak5, Av5, Ao, Ao1, Ao5, wts);
  swarm_attn_mfma<<<8192, 512, 0, stream>>>(x, L, wts, Mw);
  reduce_kernel<<<128, 256, 0, stream>>>(Mw, rsw, csw);
  expand_kernel<<<8192, 256, 0, stream>>>(Mw, rsw, csw, (float*)d_out);
}

// Round 16
// 310.995 us; speedup vs baseline: 1.3475x; 1.0119x over previous
//
#include <hip/hip_runtime.h>

typedef _Float16 f16;
typedef __attribute__((ext_vector_type(8))) _Float16 h8v;   // 8 fp16 = 4 VGPR
typedef __attribute__((ext_vector_type(4))) float f4v;      // 16x16 accumulator
typedef __attribute__((ext_vector_type(16))) float f16acc;  // 32x32 accumulator

// fp16 weight workspace layout (elements) — frag-major.
// Q/K/V matrices are PRE-SCALED by -log2(e) so sigmoid = rcp(1+exp2(u)).
#define OFF_WQ  0
#define OFF_WK  2048
#define OFF_WV  4096
#define OFF_AQ1 6144
#define OFF_AK1 22528
#define OFF_AV1 38912
#define OFF_AQ5 55296
#define OFF_AK5 71680
#define OFF_AV5 88064
#define OFF_AO  104448
#define OFF_AO1 120832
#define OFF_AO5 137216      // Ao5 row-major 16x128 (unscaled)
#define WTS_TOTAL 139264

// Padded LDS pitches (f16 elems): rows rotate banks, offsets stay literal.
#define P2 136   // 272 B rows for [64][128] buffers (Xt/Qt/Kt)
#define P1 72    // 144 B rows for V [128][64] and P [64][64]

__device__ __forceinline__ f4v mfma16_(h8v a, h8v b, f4v c) {
  return __builtin_amdgcn_mfma_f32_16x16x32_f16(a, b, c, 0, 0, 0);
}
__device__ __forceinline__ f16acc mfma32_(h8v a, h8v b, f16acc c) {
  return __builtin_amdgcn_mfma_f32_32x32x16_f16(a, b, c, 0, 0, 0);
}
__device__ __forceinline__ float rcp_(float x) { return __builtin_amdgcn_rcpf(x); }
__device__ __forceinline__ float ex2_(float x) {
#if __has_builtin(__builtin_amdgcn_exp2f)
  return __builtin_amdgcn_exp2f(x);      // raw v_exp_f32 (2^x)
#else
  return __expf(x * 0.6931471805599453f);
#endif
}
__device__ __forceinline__ unsigned int pk2(float a, float b) {
  __fp16 __attribute__((ext_vector_type(2))) h2 = __builtin_amdgcn_cvt_pkrtz(a, b);
  return *reinterpret_cast<unsigned int*>(&h2);
}
__device__ __forceinline__ f16acc zero16() {
  f16acc z;
  #pragma unroll
  for (int i = 0; i < 16; ++i) z[i] = 0.f;
  return z;
}

// ACT 0: sigmoid on PRE-SCALED input u (= -log2e * t): rcp(1+2^u)
// ACT 1: silu on natural t. ACT 2: none.
template<int ACT>
__device__ __forceinline__ unsigned long long pack4act(float a, float b, float c, float d) {
  float v[4] = {a, b, c, d};
  #pragma unroll
  for (int j = 0; j < 4; ++j) {
    float t = v[j];
    if (ACT == 0)      t = rcp_(1.0f + ex2_(t));
    else if (ACT == 1) t = t * rcp_(1.0f + ex2_(t * -1.44269504f));
    v[j] = t;
  }
  union { unsigned long long u64; unsigned int u32[2]; } u;
  u.u32[0] = pk2(v[0], v[1]);
  u.u32[1] = pk2(v[2], v[3]);
  return u.u64;
}

// Fused Q,K,V via 32x32x16. Wave w: (rt=w>>1, ct=w&1). X-frags shared by Q/K/V.
// Q^T,K^T -> [n][r] P2; V -> [r][m] P1. All sigmoid (prescaled-domain).
template<int NKK>   // K = NKK*16
__device__ __forceinline__ void qkv_ph(const f16* __restrict__ Wq,
                                       const f16* __restrict__ Wk,
                                       const f16* __restrict__ Wv,
                                       const f16* __restrict__ Xt,
                                       f16* __restrict__ Qt, f16* __restrict__ Kt,
                                       f16* __restrict__ Vb, int w, int lane)
{
  const int l31 = lane & 31, lh = lane >> 5;
  const int rt = w >> 1, ct = w & 1;
  const int xbase = (ct * 32 + l31) * P2 + lh * 8;
  f16acc aq = zero16(), ak = zero16(), av = zero16();
  #pragma unroll
  for (int kk = 0; kk < NKK; ++kk) {
    h8v xf = *(const h8v*)(Xt + xbase + kk * 16);
    const int fo = (rt * NKK + kk) * 512 + lane * 8;
    h8v fq = *(const h8v*)(Wq + fo);
    h8v fk = *(const h8v*)(Wk + fo);
    h8v fv = *(const h8v*)(Wv + fo);
    aq = mfma32_(fq, xf, aq);
    ak = mfma32_(fk, xf, ak);
    av = mfma32_(xf, fv, av);     // V^T = X^T · Wv^T
  }
  const int nrow = (ct * 32 + l31) * P2;
  const int vrow = (rt * 32 + l31) * P1 + ct * 32 + lh * 4;
  #pragma unroll
  for (int q = 0; q < 4; ++q) {
    const int rr = rt * 32 + q * 8 + lh * 4;
    *(unsigned long long*)(Qt + nrow + rr) =
        pack4act<0>(aq[4*q], aq[4*q+1], aq[4*q+2], aq[4*q+3]);
    *(unsigned long long*)(Kt + nrow + rr) =
        pack4act<0>(ak[4*q], ak[4*q+1], ak[4*q+2], ak[4*q+3]);
    *(unsigned long long*)(Vb + vrow + q * 8) =
        pack4act<0>(av[4*q], av[4*q+1], av[4*q+2], av[4*q+3]);
  }
}

// Softmax, all 8 waves, NO max pass (f32 range analysis: t <= ~48 -> 2^48 ok),
// ONE internal barrier (sum broadcast). Wave (nst=w&3, mh=w>>2).
// Base-2 domain: p = 2^(S*is2) / sum.
__device__ __forceinline__ void softmax_ph(const f16* __restrict__ Qt,
                                           const f16* __restrict__ Kt,
                                           f16* Ps, float* __restrict__ ssum,
                                           float is2, int w, int lane)
{
  const int lrow = lane & 15, lk = lane >> 4;
  const int nst = w & 3, mh = w >> 2;
  const int n = nst * 16 + lrow;
  h8v bq[4];
  #pragma unroll
  for (int kk = 0; kk < 4; ++kk)
    bq[kk] = *(const h8v*)(Qt + n * P2 + kk * 32 + lk * 8);
  f4v acc[2];
  #pragma unroll
  for (int t = 0; t < 2; ++t) {
    const int mt = mh * 2 + t;
    acc[t] = (f4v){0.f, 0.f, 0.f, 0.f};
    #pragma unroll
    for (int kk = 0; kk < 4; ++kk) {
      h8v a = *(const h8v*)(Kt + (mt * 16 + lrow) * P2 + kk * 32 + lk * 8);
      acc[t] = mfma16_(a, bq[kk], acc[t]);
    }
  }
  float sm = 0.f;
  #pragma unroll
  for (int t = 0; t < 2; ++t)
    #pragma unroll
    for (int j = 0; j < 4; ++j) { acc[t][j] = ex2_(acc[t][j] * is2); sm += acc[t][j]; }
  sm += __shfl_xor(sm, 16);
  sm += __shfl_xor(sm, 32);
  if (lk == 0) ssum[mh * 64 + n] = sm;
  __syncthreads();
  const float inv = rcp_(ssum[n] + ssum[64 + n]);
  #pragma unroll
  for (int t = 0; t < 2; ++t) {
    const int mt = mh * 2 + t;
    union { unsigned long long u64; unsigned int u32[2]; } u;
    u.u32[0] = pk2(acc[t][0] * inv, acc[t][1] * inv);
    u.u32[1] = pk2(acc[t][2] * inv, acc[t][3] * inv);
    *(unsigned long long*)(Ps + n * P1 + mt * 16 + lk * 4) = u.u64;
  }
}

// O = V @ P^T via 32x32x16, K=64. Output O^T[n][r] (P2), no act.
__device__ __forceinline__ void pv_ph(const f16* __restrict__ Vb,
                                      const f16* __restrict__ Ps,
                                      f16* __restrict__ Ot, int w, int lane)
{
  const int l31 = lane & 31, lh = lane >> 5;
  const int rt = w >> 1, ct = w & 1;
  f16acc acc = zero16();
  #pragma unroll
  for (int kk = 0; kk < 4; ++kk) {
    h8v a = *(const h8v*)(Vb + (rt * 32 + l31) * P1 + kk * 16 + lh * 8);
    h8v b = *(const h8v*)(Ps + (ct * 32 + l31) * P1 + kk * 16 + lh * 8);
    acc = mfma32_(a, b, acc);
  }
  const int nrow = (ct * 32 + l31) * P2;
  #pragma unroll
  for (int q = 0; q < 4; ++q)
    *(unsigned long long*)(Ot + nrow + rt * 32 + q * 8 + lh * 4) =
        pack4act<2>(acc[4*q], acc[4*q+1], acc[4*q+2], acc[4*q+3]);
}

// R = silu(Ao @ O) via 32x32x16, K=128. Output R^T[n][s] (P2) -> Rt.
__device__ __forceinline__ void ao_ph(const f16* __restrict__ Ao,
                                      const f16* __restrict__ Ot,
                                      f16* __restrict__ Rt, int w, int lane)
{
  const int l31 = lane & 31, lh = lane >> 5;
  const int st = w >> 1, ct = w & 1;
  f16acc acc = zero16();
  #pragma unroll
  for (int kk = 0; kk < 8; ++kk) {
    h8v a = *(const h8v*)(Ao + (st * 8 + kk) * 512 + lane * 8);
    h8v b = *(const h8v*)(Ot + (ct * 32 + l31) * P2 + kk * 16 + lh * 8);
    acc = mfma32_(a, b, acc);
  }
  const int nrow = (ct * 32 + l31) * P2;
  #pragma unroll
  for (int q = 0; q < 4; ++q)
    *(unsigned long long*)(Rt + nrow + st * 32 + q * 8 + lh * 4) =
        pack4act<1>(acc[4*q], acc[4*q+1], acc[4*q+2], acc[4*q+3]);
}

// Final (Mw-fused): M[g][i][n] = sum_j silu(Ao5 @ O)[g*4+j][n] — channel-sum
// done in-register. Waves 0..3 (n-strip w); lane: g=lk, n=16w+lrow.
// Mw layout: [s][g][i][n], s = b>>6, i = b&63.
__device__ __forceinline__ void final_ph(const f16* __restrict__ Ao5g,
                                         const f16* __restrict__ Ot,
                                         float* __restrict__ Mw, int b, int w, int lane)
{
  const int lrow = lane & 15, lk = lane >> 4;
  h8v a[4];
  #pragma unroll
  for (int kk = 0; kk < 4; ++kk)
    a[kk] = *(const h8v*)(Ao5g + lrow * 128 + kk * 32 + lk * 8);
  const int n = 16 * w + lrow;
  f4v acc = {0.f, 0.f, 0.f, 0.f};
  #pragma unroll
  for (int kk = 0; kk < 4; ++kk) {
    h8v bb = *(const h8v*)(Ot + n * P2 + kk * 32 + lk * 8);
    acc = mfma16_(a[kk], bb, acc);
  }
  float msum = 0.f;
  #pragma unroll
  for (int j = 0; j < 4; ++j) {
    float v = acc[j];
    v = v * rcp_(1.0f + ex2_(v * -1.44269504f));
    msum += v;                     // sum over s = lk*4+j within channel-group lk
  }
  Mw[(size_t)(b >> 6) * 16384 + lk * 4096 + (b & 63) * 64 + n] = msum;
}

__global__ __launch_bounds__(512, 4)
void swarm_attn_mfma(const float* __restrict__ x, const float* __restrict__ L,
                     const f16* __restrict__ wts, float* __restrict__ Mw)
{
  __shared__ f16 Xt[64 * P2];    // X^T / R^T [n][k]; Ps aliases this buffer
  __shared__ f16 Qt[64 * P2];    // Q^T [n][r]; reused as O^T after softmax
  __shared__ f16 Kt[64 * P2];    // K^T [m][r]
  __shared__ f16 Vb[128 * P1];   // V [r][m]
  __shared__ float ssum[2 * 64];
  f16* Ps = Xt;                  // P [n][m] pitch P1 (Xt dead during softmax/PV)

  const int b = blockIdx.x;
  const int tid = threadIdx.x;
  const int w = tid >> 6, lane = tid & 63;

  // stage layer-1 X^T [n][f], zero-padded to K=16
  {
    const int n = tid >> 3, c = tid & 7;
    unsigned int val = 0;
    if (c < 4) {
      const float a  = x[(size_t)b * 512 + (2 * c) * 64 + n];
      const float bb = x[(size_t)b * 512 + (2 * c + 1) * 64 + n];
      val = pk2(a, bb);
    }
    *(unsigned int*)(Xt + n * P2 + 2 * c) = val;
  }
  // every wave computes is2 itself (L is L2-resident; no LDS broadcast needed)
  const float lv = L[(size_t)b * 512 + lane];
  const unsigned long long msk = __ballot(lv >= 1.0f);
  const float is2 = __frsqrt_rn((float)(__popcll(msk) + 1)) * 1.44269504f;
  __syncthreads();

  // -------- Layer 1 (K = 16 padded) --------
  qkv_ph<1>(wts + OFF_WQ, wts + OFF_WK, wts + OFF_WV, Xt, Qt, Kt, Vb, w, lane);
  __syncthreads();
  softmax_ph(Qt, Kt, Ps, ssum, is2, w, lane);
  __syncthreads();
  pv_ph(Vb, Ps, Qt, w, lane);                 // O^T -> Qt
  __syncthreads();
  ao_ph(wts + OFF_AO, Qt, Xt, w, lane);       // R^T -> Xt
  __syncthreads();

  // -------- Layer 2 (K = 128) --------
  qkv_ph<8>(wts + OFF_AQ1, wts + OFF_AK1, wts + OFF_AV1, Xt, Qt, Kt, Vb, w, lane);
  __syncthreads();
  softmax_ph(Qt, Kt, Ps, ssum, is2, w, lane);
  __syncthreads();
  pv_ph(Vb, Ps, Qt, w, lane);
  __syncthreads();
  ao_ph(wts + OFF_AO1, Qt, Xt, w, lane);
  __syncthreads();

  // -------- Layer 3 (K = 128) --------
  qkv_ph<8>(wts + OFF_AQ5, wts + OFF_AK5, wts + OFF_AV5, Xt, Qt, Kt, Vb, w, lane);
  __syncthreads();
  softmax_ph(Qt, Kt, Ps, ssum, is2, w, lane);
  __syncthreads();
  pv_ph(Vb, Ps, Qt, w, lane);
  __syncthreads();
  if (w < 4) final_ph(wts + OFF_AO5, Qt, Mw, b, w, lane);
}

// Convert weights to fp16, frag-major; Q/K/V matrices pre-scaled by -log2(e).
__global__ void conv_wts(const float* Aq, const float* Ak, const float* Av,
                         const float* Aq1, const float* Ak1, const float* Av1,
                         const float* Aq5, const float* Ak5, const float* Av5,
                         const float* Ao, const float* Ao1, const float* Ao5,
                         f16* wts)
{
  const float SCL = -1.44269504088896f;
  const int t = blockIdx.x * 256 + threadIdx.x;
  if (t >= WTS_TOTAL) return;
  float v;
  if (t < 6144) {                       // L1: 128x16 (padded from 8), 4 frags x 512
    const int m = t >> 11, idx = t & 2047;
    const int fi = idx >> 9, rem = idx & 511, lane = rem >> 3, j = rem & 7;
    const int r = fi * 32 + (lane & 31), k = (lane >> 5) * 8 + j;
    const float* W = (m == 0) ? Aq : (m == 1) ? Ak : Av;
    v = (k < 8) ? W[r * 8 + k] * SCL : 0.f;
  } else if (t < 137216) {              // 8 matrices 128x128, 32 frags each
    const int m = (t - 6144) >> 14, idx = (t - 6144) & 16383;
    const int fi = idx >> 9, rem = idx & 511, lane = rem >> 3, j = rem & 7;
    const int rt = fi >> 3, kk = fi & 7;
    const int r = rt * 32 + (lane & 31), k = kk * 16 + (lane >> 5) * 8 + j;
    const float* W = (m == 0) ? Aq1 : (m == 1) ? Ak1 : (m == 2) ? Av1 :
                     (m == 3) ? Aq5 : (m == 4) ? Ak5 : (m == 5) ? Av5 :
                     (m == 6) ? Ao : Ao1;
    v = W[r * 128 + k];
    if (m < 6) v *= SCL;                // sigmoid inputs only
  } else {
    v = Ao5[t - 137216];
  }
  wts[t] = (f16)v;
}

// Stage A (parallelized): one block per (s,g) 64x64 M-tile; 4 waves.
// Lane (wave wv, lane l): i = wv*16 + (l&15), quarter q = l>>4 handles 16 j's
// of both the row-sum (M[i][j]^2) and col-sum (M[j][i]^2); fold q via shfl_xor.
// No LDS, no barrier.
__global__ __launch_bounds__(256, 4)
void reduce_kernel(const float* __restrict__ Mw,
                   float* __restrict__ rsw, float* __restrict__ csw)
{
  const int sg = blockIdx.x;                       // s*4 + g
  const float* M = Mw + (size_t)sg * 4096;
  const int wv = threadIdx.x >> 6, l = threadIdx.x & 63;
  const int i = wv * 16 + (l & 15), q = l >> 4;
  float r2 = 0.f, c2 = 0.f;
  #pragma unroll
  for (int jj = 0; jj < 16; ++jj) {
    const float a = M[i * 64 + q * 16 + jj];       // row i, cols q*16..q*16+15
    r2 = fmaf(a, a, r2);
    const float bc = M[(q * 16 + jj) * 64 + i];    // col i, rows q*16..q*16+15
    c2 = fmaf(bc, bc, c2);
  }
  r2 += __shfl_xor(r2, 16); r2 += __shfl_xor(r2, 32);
  c2 += __shfl_xor(c2, 16); c2 += __shfl_xor(c2, 32);
  if (q == 0) {
    const int s = sg >> 2, g = sg & 3;
    rsw[s * 256 + g * 64 + i] = r2;
    csw[s * 256 + g * 64 + i] = c2;
  }
}

// Stage B: fully-parallel expansion to the 256x256 output per swarm
__global__ __launch_bounds__(256, 1)
void expand_kernel(const float* __restrict__ Mw, const float* __restrict__ rsw,
                   const float* __restrict__ csw, float* __restrict__ out)
{
  const size_t e = ((size_t)blockIdx.x * 256 + threadIdx.x) * 4;
  const int s = (int)(e >> 16);
  const int rem = (int)(e & 65535);
  const int u = rem >> 8, v0 = rem & 255;
  const int ub = u >> 7, ii = (u & 127) >> 1, p = u & 1;
  const float* Ms = Mw + (size_t)s * 16384;
  float4 o;
  float* po = &o.x;
  #pragma unroll
  for (int c = 0; c < 4; ++c) {
    const int v = v0 + c;
    const int vb = v >> 7, jj = (v & 127) >> 1, q = v & 1;
    float val = 0.f;
    if (u == v) {
      val = rsw[s * 256 + (2 * ub) * 64 + ii] + rsw[s * 256 + (2 * ub + 1) * 64 + ii]
          + csw[s * 256 + ub * 64 + ii] + csw[s * 256 + (2 + ub) * 64 + ii];
    } else if (p == q) {
      const int g = 2 * ub + vb, gp = 2 * vb + ub;
      const float a = Ms[g * 4096 + ii * 64 + jj];
      const float bb = Ms[gp * 4096 + jj * 64 + ii];
      val = -(a * a + bb * bb);
    }
    po[c] = val;
  }
  *(float4*)(out + e) = o;
}

extern "C" void kernel_launch(void* const* d_in, const int* in_sizes, int n_in,
                              void* d_out, int out_size, void* d_ws, size_t ws_size,
                              hipStream_t stream)
{
  const float* x   = (const float*)d_in[0];
  const float* L   = (const float*)d_in[1];
  const float* Aq  = (const float*)d_in[2];
  const float* Ak  = (const float*)d_in[3];
  const float* Av  = (const float*)d_in[4];
  const float* Aq1 = (const float*)d_in[5];
  const float* Ak1 = (const float*)d_in[6];
  const float* Av1 = (const float*)d_in[7];
  const float* Aq5 = (const float*)d_in[8];
  const float* Ak5 = (const float*)d_in[9];
  const float* Av5 = (const float*)d_in[10];
  const float* Ao  = (const float*)d_in[11];
  const float* Ao1 = (const float*)d_in[12];
  const float* Ao5 = (const float*)d_in[13];

  // ws: fp16 weights (278528 B) | Mw 128*16384 f32 | rsw | csw
  f16* wts = (f16*)d_ws;
  float* Mw  = (float*)((char*)d_ws + (size_t)WTS_TOTAL * 2);
  float* rsw = Mw + (size_t)128 * 16384;
  float* csw = rsw + 128 * 256;

  conv_wts<<<(WTS_TOTAL + 255) / 256, 256, 0, stream>>>(Aq, Ak, Av, Aq1, Ak1, Av1,
                                                        Aq5, Ak5, Av5, Ao, Ao1, Ao5, wts);
  swarm_attn_mfma<<<8192, 512, 0, stream>>>(x, L, wts, Mw);
  reduce_kernel<<<512, 256, 0, stream>>>(Mw, rsw, csw);
  expand_kernel<<<8192, 256, 0, stream>>>(Mw, rsw, csw, (float*)d_out);
}

// Round 17
// 305.042 us; speedup vs baseline: 1.3738x; 1.0195x over previous
//
#include <hip/hip_runtime.h>

typedef _Float16 f16;
typedef __attribute__((ext_vector_type(8))) _Float16 h8v;   // 8 fp16 = 4 VGPR
typedef __attribute__((ext_vector_type(4))) float f4v;      // 16x16 accumulator
typedef __attribute__((ext_vector_type(16))) float f16acc;  // 32x32 accumulator

// fp16 weight workspace layout (elements) — frag-major.
// Q/K/V matrices are PRE-SCALED by -log2(e) so sigmoid = rcp(1+exp2(u)).
#define OFF_WQ  0
#define OFF_WK  2048
#define OFF_WV  4096
#define OFF_AQ1 6144
#define OFF_AK1 22528
#define OFF_AV1 38912
#define OFF_AQ5 55296
#define OFF_AK5 71680
#define OFF_AV5 88064
#define OFF_AO  104448
#define OFF_AO1 120832
#define OFF_AO5 137216      // Ao5 row-major 16x128 (unscaled)
#define WTS_TOTAL 139264

// Padded LDS pitches (f16 elems): rows rotate banks, offsets stay literal.
#define P2 136   // 272 B rows for [64][128] buffers (Xt/Qt/Kt)
#define P1 72    // 144 B rows for V [128][64] and P [64][64]

__device__ __forceinline__ f4v mfma16_(h8v a, h8v b, f4v c) {
  return __builtin_amdgcn_mfma_f32_16x16x32_f16(a, b, c, 0, 0, 0);
}
__device__ __forceinline__ f16acc mfma32_(h8v a, h8v b, f16acc c) {
  return __builtin_amdgcn_mfma_f32_32x32x16_f16(a, b, c, 0, 0, 0);
}
__device__ __forceinline__ float rcp_(float x) { return __builtin_amdgcn_rcpf(x); }
__device__ __forceinline__ float ex2_(float x) {
#if __has_builtin(__builtin_amdgcn_exp2f)
  return __builtin_amdgcn_exp2f(x);      // raw v_exp_f32 (2^x)
#else
  return __expf(x * 0.6931471805599453f);
#endif
}
__device__ __forceinline__ unsigned int pk2(float a, float b) {
  __fp16 __attribute__((ext_vector_type(2))) h2 = __builtin_amdgcn_cvt_pkrtz(a, b);
  return *reinterpret_cast<unsigned int*>(&h2);
}
__device__ __forceinline__ f16acc zero16() {
  f16acc z;
  #pragma unroll
  for (int i = 0; i < 16; ++i) z[i] = 0.f;
  return z;
}

// ACT 0: sigmoid on PRE-SCALED input u (= -log2e * t): rcp(1+2^u)
// ACT 1: silu on natural t. ACT 2: none.
template<int ACT>
__device__ __forceinline__ unsigned long long pack4act(float a, float b, float c, float d) {
  float v[4] = {a, b, c, d};
  #pragma unroll
  for (int j = 0; j < 4; ++j) {
    float t = v[j];
    if (ACT == 0)      t = rcp_(1.0f + ex2_(t));
    else if (ACT == 1) t = t * rcp_(1.0f + ex2_(t * -1.44269504f));
    v[j] = t;
  }
  union { unsigned long long u64; unsigned int u32[2]; } u;
  u.u32[0] = pk2(v[0], v[1]);
  u.u32[1] = pk2(v[2], v[3]);
  return u.u64;
}

// Fused Q,K,V via 32x32x16. Wave w: (rt=w>>1, ct=w&1). X-frags shared by Q/K/V.
// Q^T,K^T -> [n][r] P2; V -> [r][m] P1. All sigmoid (prescaled-domain).
template<int NKK>   // K = NKK*16
__device__ __forceinline__ void qkv_ph(const f16* __restrict__ Wq,
                                       const f16* __restrict__ Wk,
                                       const f16* __restrict__ Wv,
                                       const f16* __restrict__ Xt,
                                       f16* __restrict__ Qt, f16* __restrict__ Kt,
                                       f16* __restrict__ Vb, int w, int lane)
{
  const int l31 = lane & 31, lh = lane >> 5;
  const int rt = w >> 1, ct = w & 1;
  const int xbase = (ct * 32 + l31) * P2 + lh * 8;
  f16acc aq = zero16(), ak = zero16(), av = zero16();
  #pragma unroll
  for (int kk = 0; kk < NKK; ++kk) {
    h8v xf = *(const h8v*)(Xt + xbase + kk * 16);
    const int fo = (rt * NKK + kk) * 512 + lane * 8;
    h8v fq = *(const h8v*)(Wq + fo);
    h8v fk = *(const h8v*)(Wk + fo);
    h8v fv = *(const h8v*)(Wv + fo);
    aq = mfma32_(fq, xf, aq);
    ak = mfma32_(fk, xf, ak);
    av = mfma32_(xf, fv, av);     // V^T = X^T · Wv^T
  }
  const int nrow = (ct * 32 + l31) * P2;
  const int vrow = (rt * 32 + l31) * P1 + ct * 32 + lh * 4;
  #pragma unroll
  for (int q = 0; q < 4; ++q) {
    const int rr = rt * 32 + q * 8 + lh * 4;
    *(unsigned long long*)(Qt + nrow + rr) =
        pack4act<0>(aq[4*q], aq[4*q+1], aq[4*q+2], aq[4*q+3]);
    *(unsigned long long*)(Kt + nrow + rr) =
        pack4act<0>(ak[4*q], ak[4*q+1], ak[4*q+2], ak[4*q+3]);
    *(unsigned long long*)(Vb + vrow + q * 8) =
        pack4act<0>(av[4*q], av[4*q+1], av[4*q+2], av[4*q+3]);
  }
}

// Softmax, all 8 waves, NO max pass (f32 range analysis: t <= ~48 -> 2^48 ok),
// ONE internal barrier (sum broadcast). Wave (nst=w&3, mh=w>>2).
// Base-2 domain: p = 2^(S*is2) / sum.
__device__ __forceinline__ void softmax_ph(const f16* __restrict__ Qt,
                                           const f16* __restrict__ Kt,
                                           f16* Ps, float* __restrict__ ssum,
                                           float is2, int w, int lane)
{
  const int lrow = lane & 15, lk = lane >> 4;
  const int nst = w & 3, mh = w >> 2;
  const int n = nst * 16 + lrow;
  h8v bq[4];
  #pragma unroll
  for (int kk = 0; kk < 4; ++kk)
    bq[kk] = *(const h8v*)(Qt + n * P2 + kk * 32 + lk * 8);
  f4v acc[2];
  #pragma unroll
  for (int t = 0; t < 2; ++t) {
    const int mt = mh * 2 + t;
    acc[t] = (f4v){0.f, 0.f, 0.f, 0.f};
    #pragma unroll
    for (int kk = 0; kk < 4; ++kk) {
      h8v a = *(const h8v*)(Kt + (mt * 16 + lrow) * P2 + kk * 32 + lk * 8);
      acc[t] = mfma16_(a, bq[kk], acc[t]);
    }
  }
  float sm = 0.f;
  #pragma unroll
  for (int t = 0; t < 2; ++t)
    #pragma unroll
    for (int j = 0; j < 4; ++j) { acc[t][j] = ex2_(acc[t][j] * is2); sm += acc[t][j]; }
  sm += __shfl_xor(sm, 16);
  sm += __shfl_xor(sm, 32);
  if (lk == 0) ssum[mh * 64 + n] = sm;
  __syncthreads();
  const float inv = rcp_(ssum[n] + ssum[64 + n]);
  #pragma unroll
  for (int t = 0; t < 2; ++t) {
    const int mt = mh * 2 + t;
    union { unsigned long long u64; unsigned int u32[2]; } u;
    u.u32[0] = pk2(acc[t][0] * inv, acc[t][1] * inv);
    u.u32[1] = pk2(acc[t][2] * inv, acc[t][3] * inv);
    *(unsigned long long*)(Ps + n * P1 + mt * 16 + lk * 4) = u.u64;
  }
}

// O = V @ P^T via 32x32x16, K=64. Output O^T[n][r] (P2), no act.
__device__ __forceinline__ void pv_ph(const f16* __restrict__ Vb,
                                      const f16* __restrict__ Ps,
                                      f16* __restrict__ Ot, int w, int lane)
{
  const int l31 = lane & 31, lh = lane >> 5;
  const int rt = w >> 1, ct = w & 1;
  f16acc acc = zero16();
  #pragma unroll
  for (int kk = 0; kk < 4; ++kk) {
    h8v a = *(const h8v*)(Vb + (rt * 32 + l31) * P1 + kk * 16 + lh * 8);
    h8v b = *(const h8v*)(Ps + (ct * 32 + l31) * P1 + kk * 16 + lh * 8);
    acc = mfma32_(a, b, acc);
  }
  const int nrow = (ct * 32 + l31) * P2;
  #pragma unroll
  for (int q = 0; q < 4; ++q)
    *(unsigned long long*)(Ot + nrow + rt * 32 + q * 8 + lh * 4) =
        pack4act<2>(acc[4*q], acc[4*q+1], acc[4*q+2], acc[4*q+3]);
}

// R = silu(Ao @ O) via 32x32x16, K=128. Output R^T[n][s] (P2) -> Rt.
__device__ __forceinline__ void ao_ph(const f16* __restrict__ Ao,
                                      const f16* __restrict__ Ot,
                                      f16* __restrict__ Rt, int w, int lane)
{
  const int l31 = lane & 31, lh = lane >> 5;
  const int st = w >> 1, ct = w & 1;
  f16acc acc = zero16();
  #pragma unroll
  for (int kk = 0; kk < 8; ++kk) {
    h8v a = *(const h8v*)(Ao + (st * 8 + kk) * 512 + lane * 8);
    h8v b = *(const h8v*)(Ot + (ct * 32 + l31) * P2 + kk * 16 + lh * 8);
    acc = mfma32_(a, b, acc);
  }
  const int nrow = (ct * 32 + l31) * P2;
  #pragma unroll
  for (int q = 0; q < 4; ++q)
    *(unsigned long long*)(Rt + nrow + st * 32 + q * 8 + lh * 4) =
        pack4act<1>(acc[4*q], acc[4*q+1], acc[4*q+2], acc[4*q+3]);
}

// Final (Mw-fused): M[g][i][n] = sum_j silu(Ao5 @ O)[g*4+j][n] — channel-sum
// done in-register. Waves 0..3 (n-strip w); lane: g=lk, n=16w+lrow.
// Mw layout: [s][g][i][n], s = b>>6, i = b&63.
__device__ __forceinline__ void final_ph(const f16* __restrict__ Ao5g,
                                         const f16* __restrict__ Ot,
                                         float* __restrict__ Mw, int b, int w, int lane)
{
  const int lrow = lane & 15, lk = lane >> 4;
  h8v a[4];
  #pragma unroll
  for (int kk = 0; kk < 4; ++kk)
    a[kk] = *(const h8v*)(Ao5g + lrow * 128 + kk * 32 + lk * 8);
  const int n = 16 * w + lrow;
  f4v acc = {0.f, 0.f, 0.f, 0.f};
  #pragma unroll
  for (int kk = 0; kk < 4; ++kk) {
    h8v bb = *(const h8v*)(Ot + n * P2 + kk * 32 + lk * 8);
    acc = mfma16_(a[kk], bb, acc);
  }
  float msum = 0.f;
  #pragma unroll
  for (int j = 0; j < 4; ++j) {
    float v = acc[j];
    v = v * rcp_(1.0f + ex2_(v * -1.44269504f));
    msum += v;                     // sum over s = lk*4+j within channel-group lk
  }
  Mw[(size_t)(b >> 6) * 16384 + lk * 4096 + (b & 63) * 64 + n] = msum;
}

__global__ __launch_bounds__(512, 4)
void swarm_attn_mfma(const float* __restrict__ x, const float* __restrict__ L,
                     const f16* __restrict__ wts, float* __restrict__ Mw)
{
  __shared__ f16 Xt[64 * P2];    // X^T / R^T [n][k]; Ps aliases this buffer
  __shared__ f16 Qt[64 * P2];    // Q^T [n][r]; reused as O^T after softmax
  __shared__ f16 Kt[64 * P2];    // K^T [m][r]
  __shared__ f16 Vb[128 * P1];   // V [r][m]
  __shared__ float ssum[2 * 64];
  f16* Ps = Xt;                  // P [n][m] pitch P1 (Xt dead during softmax/PV)

  const int b = blockIdx.x;
  const int tid = threadIdx.x;
  const int w = tid >> 6, lane = tid & 63;

  // stage layer-1 X^T [n][f], zero-padded to K=16
  {
    const int n = tid >> 3, c = tid & 7;
    unsigned int val = 0;
    if (c < 4) {
      const float a  = x[(size_t)b * 512 + (2 * c) * 64 + n];
      const float bb = x[(size_t)b * 512 + (2 * c + 1) * 64 + n];
      val = pk2(a, bb);
    }
    *(unsigned int*)(Xt + n * P2 + 2 * c) = val;
  }
  // every wave computes is2 itself (L is L2-resident; no LDS broadcast needed)
  const float lv = L[(size_t)b * 512 + lane];
  const unsigned long long msk = __ballot(lv >= 1.0f);
  const float is2 = __frsqrt_rn((float)(__popcll(msk) + 1)) * 1.44269504f;
  __syncthreads();

  // -------- Layer 1 (K = 16 padded) --------
  qkv_ph<1>(wts + OFF_WQ, wts + OFF_WK, wts + OFF_WV, Xt, Qt, Kt, Vb, w, lane);
  __syncthreads();
  softmax_ph(Qt, Kt, Ps, ssum, is2, w, lane);
  __syncthreads();
  pv_ph(Vb, Ps, Qt, w, lane);                 // O^T -> Qt
  __syncthreads();
  ao_ph(wts + OFF_AO, Qt, Xt, w, lane);       // R^T -> Xt
  __syncthreads();

  // -------- Layer 2 (K = 128) --------
  qkv_ph<8>(wts + OFF_AQ1, wts + OFF_AK1, wts + OFF_AV1, Xt, Qt, Kt, Vb, w, lane);
  __syncthreads();
  softmax_ph(Qt, Kt, Ps, ssum, is2, w, lane);
  __syncthreads();
  pv_ph(Vb, Ps, Qt, w, lane);
  __syncthreads();
  ao_ph(wts + OFF_AO1, Qt, Xt, w, lane);
  __syncthreads();

  // -------- Layer 3 (K = 128) --------
  qkv_ph<8>(wts + OFF_AQ5, wts + OFF_AK5, wts + OFF_AV5, Xt, Qt, Kt, Vb, w, lane);
  __syncthreads();
  softmax_ph(Qt, Kt, Ps, ssum, is2, w, lane);
  __syncthreads();
  pv_ph(Vb, Ps, Qt, w, lane);
  __syncthreads();
  if (w < 4) final_ph(wts + OFF_AO5, Qt, Mw, b, w, lane);
}

// Convert weights to fp16, frag-major; Q/K/V matrices pre-scaled by -log2(e).
__global__ void conv_wts(const float* Aq, const float* Ak, const float* Av,
                         const float* Aq1, const float* Ak1, const float* Av1,
                         const float* Aq5, const float* Ak5, const float* Av5,
                         const float* Ao, const float* Ao1, const float* Ao5,
                         f16* wts)
{
  const float SCL = -1.44269504088896f;
  const int t = blockIdx.x * 256 + threadIdx.x;
  if (t >= WTS_TOTAL) return;
  float v;
  if (t < 6144) {                       // L1: 128x16 (padded from 8), 4 frags x 512
    const int m = t >> 11, idx = t & 2047;
    const int fi = idx >> 9, rem = idx & 511, lane = rem >> 3, j = rem & 7;
    const int r = fi * 32 + (lane & 31), k = (lane >> 5) * 8 + j;
    const float* W = (m == 0) ? Aq : (m == 1) ? Ak : Av;
    v = (k < 8) ? W[r * 8 + k] * SCL : 0.f;
  } else if (t < 137216) {              // 8 matrices 128x128, 32 frags each
    const int m = (t - 6144) >> 14, idx = (t - 6144) & 16383;
    const int fi = idx >> 9, rem = idx & 511, lane = rem >> 3, j = rem & 7;
    const int rt = fi >> 3, kk = fi & 7;
    const int r = rt * 32 + (lane & 31), k = kk * 16 + (lane >> 5) * 8 + j;
    const float* W = (m == 0) ? Aq1 : (m == 1) ? Ak1 : (m == 2) ? Av1 :
                     (m == 3) ? Aq5 : (m == 4) ? Ak5 : (m == 5) ? Av5 :
                     (m == 6) ? Ao : Ao1;
    v = W[r * 128 + k];
    if (m < 6) v *= SCL;                // sigmoid inputs only
  } else {
    v = Ao5[t - 137216];
  }
  wts[t] = (f16)v;
}

// Stage A: one block per (s,g) 64x64 M-tile; 4 waves, no LDS, no barrier.
// Lane (wave wv, lane l): i = wv*16 + (l&15), quarter q = l>>4 handles 16 j's
// of row-sum (M[i][j]^2) and col-sum (M[j][i]^2); fold q via shfl_xor.
// Also emits MwT[g][i][j] = M[g][j][i] (free — the column values are in hand)
// so expand_kernel's bb-read becomes coalesced.
__global__ __launch_bounds__(256, 4)
void reduce_kernel(const float* __restrict__ Mw, float* __restrict__ MwT,
                   float* __restrict__ rsw, float* __restrict__ csw)
{
  const int sg = blockIdx.x;                       // s*4 + g
  const float* M = Mw + (size_t)sg * 4096;
  const int wv = threadIdx.x >> 6, l = threadIdx.x & 63;
  const int i = wv * 16 + (l & 15), q = l >> 4;
  float r2 = 0.f, c2 = 0.f;
  float colv[16];
  #pragma unroll
  for (int jj = 0; jj < 16; ++jj) {
    const float a = M[i * 64 + q * 16 + jj];       // row i, cols q*16..q*16+15
    r2 = fmaf(a, a, r2);
    const float bc = M[(q * 16 + jj) * 64 + i];    // col i, rows q*16..q*16+15
    c2 = fmaf(bc, bc, c2);
    colv[jj] = bc;
  }
  if (MwT) {
    float* MT = MwT + (size_t)sg * 4096 + i * 64 + q * 16;
    #pragma unroll
    for (int jj = 0; jj < 16; ++jj) MT[jj] = colv[jj];   // MwT[i][j] = M[j][i]
  }
  r2 += __shfl_xor(r2, 16); r2 += __shfl_xor(r2, 32);
  c2 += __shfl_xor(c2, 16); c2 += __shfl_xor(c2, 32);
  if (q == 0) {
    const int s = sg >> 2, g = sg & 3;
    rsw[s * 256 + g * 64 + i] = r2;
    csw[s * 256 + g * 64 + i] = c2;
  }
}

// Stage B: fully-parallel expansion to the 256x256 output per swarm.
// bb comes from MwT (coalesced) when available, else the strided fallback.
__global__ __launch_bounds__(256, 1)
void expand_kernel(const float* __restrict__ Mw, const float* __restrict__ MwT,
                   const float* __restrict__ rsw, const float* __restrict__ csw,
                   float* __restrict__ out)
{
  const size_t e = ((size_t)blockIdx.x * 256 + threadIdx.x) * 4;
  const int s = (int)(e >> 16);
  const int rem = (int)(e & 65535);
  const int u = rem >> 8, v0 = rem & 255;
  const int ub = u >> 7, ii = (u & 127) >> 1, p = u & 1;
  const float* Ms = Mw + (size_t)s * 16384;
  const float* MsT = MwT ? MwT + (size_t)s * 16384 : nullptr;
  float4 o;
  float* po = &o.x;
  #pragma unroll
  for (int c = 0; c < 4; ++c) {
    const int v = v0 + c;
    const int vb = v >> 7, jj = (v & 127) >> 1, q = v & 1;
    float val = 0.f;
    if (u == v) {
      val = rsw[s * 256 + (2 * ub) * 64 + ii] + rsw[s * 256 + (2 * ub + 1) * 64 + ii]
          + csw[s * 256 + ub * 64 + ii] + csw[s * 256 + (2 + ub) * 64 + ii];
    } else if (p == q) {
      const int g = 2 * ub + vb, gp = 2 * vb + ub;
      const float a = Ms[g * 4096 + ii * 64 + jj];
      const float bb = MsT ? MsT[gp * 4096 + ii * 64 + jj]     // coalesced
                           : Ms[gp * 4096 + jj * 64 + ii];     // strided fallback
      val = -(a * a + bb * bb);
    }
    po[c] = val;
  }
  *(float4*)(out + e) = o;
}

extern "C" void kernel_launch(void* const* d_in, const int* in_sizes, int n_in,
                              void* d_out, int out_size, void* d_ws, size_t ws_size,
                              hipStream_t stream)
{
  const float* x   = (const float*)d_in[0];
  const float* L   = (const float*)d_in[1];
  const float* Aq  = (const float*)d_in[2];
  const float* Ak  = (const float*)d_in[3];
  const float* Av  = (const float*)d_in[4];
  const float* Aq1 = (const float*)d_in[5];
  const float* Ak1 = (const float*)d_in[6];
  const float* Av1 = (const float*)d_in[7];
  const float* Aq5 = (const float*)d_in[8];
  const float* Ak5 = (const float*)d_in[9];
  const float* Av5 = (const float*)d_in[10];
  const float* Ao  = (const float*)d_in[11];
  const float* Ao1 = (const float*)d_in[12];
  const float* Ao5 = (const float*)d_in[13];

  // ws: fp16 weights (278528 B) | Mw 8.39MB | rsw 128KB | csw 128KB | MwT 8.39MB
  f16* wts = (f16*)d_ws;
  float* Mw  = (float*)((char*)d_ws + (size_t)WTS_TOTAL * 2);
  float* rsw = Mw + (size_t)128 * 16384;
  float* csw = rsw + 128 * 256;
  float* MwT = csw + 128 * 256;
  const size_t need = (size_t)WTS_TOTAL * 2 +
                      ((size_t)128 * 16384 * 2 + 2 * 128 * 256) * sizeof(float);
  float* MwTp = (ws_size >= need) ? MwT : nullptr;

  conv_wts<<<(WTS_TOTAL + 255) / 256, 256, 0, stream>>>(Aq, Ak, Av, Aq1, Ak1, Av1,
                                                        Aq5, Ak5, Av5, Ao, Ao1, Ao5, wts);
  swarm_attn_mfma<<<8192, 512, 0, stream>>>(x, L, wts, Mw);
  reduce_kernel<<<512, 256, 0, stream>>>(Mw, MwTp, rsw, csw);
  expand_kernel<<<8192, 256, 0, stream>>>(Mw, MwTp, rsw, csw, (float*)d_out);
}